// Round 4
// baseline (2720.107 us; speedup 1.0000x reference)
//
#include <hip/hip_runtime.h>
#include <math.h>

#define N_ 64
#define C_ 256
#define T_ 64
#define V_ 25
#define H_ 3
#define O_ 256
#define D_ 32
#define HD_ 96
#define XS 260          // xbT row stride in floats (16B-aligned rows, spreads banks)
#define BN_EPS 1e-5f

__global__ __launch_bounds__(256)
void hdgc_fused(const float* __restrict__ x,
                const float* __restrict__ A_prior,
                const float* __restrict__ A_2hop,
                const float* __restrict__ beta_p,
                const float* __restrict__ lam_p,
                const float* __restrict__ W_phi,
                const float* __restrict__ b_phi,
                const float* __restrict__ W_psi,
                const float* __restrict__ b_psi,
                const float* __restrict__ W_d,
                const float* __restrict__ b_d,
                const float* __restrict__ bn_gamma,
                const float* __restrict__ bn_beta,
                const float* __restrict__ bn_mean,
                const float* __restrict__ bn_var,
                const float* __restrict__ W_g,
                const float* __restrict__ b_g,
                float* __restrict__ out)
{
    __shared__ float xbT[V_ * XS];        // 6500 f : x slice, [v][c]
    __shared__ float phi[HD_ * V_];       // 2400 f : [e][v]
    __shared__ float psi[HD_ * V_];       // 2400 f : [e][v]
    __shared__ float Afin[H_ * V_ * V_];  // 1875 f : [h][v][w]

    const int tid = threadIdx.x;
    const int b = blockIdx.x;
    const int n = b / T_;
    const int t = b - n * T_;
    // x[n,c,t,v] flat = n*C*T*V + c*T*V + t*V + v
    const size_t xbase = (size_t)n * (C_ * T_ * V_) + (size_t)t * V_;

    // ---- 1. load x slice into LDS, transposed to [v][c] ----
    for (int i = tid; i < C_ * V_; i += 256) {
        int c = i / V_;
        int v = i - c * V_;
        xbT[v * XS + c] = x[xbase + (size_t)c * (T_ * V_) + v];
    }
    __syncthreads();

    // ---- 2. phi / psi projections: [e][v] = W[e,:] . xb[:,v] + b[e] ----
    for (int i = tid; i < 2 * HD_ * V_; i += 256) {
        int m = i / (HD_ * V_);
        int j = i - m * (HD_ * V_);
        int e = j / V_;
        int v = j - e * V_;
        const float* W = m ? W_psi : W_phi;
        float s = m ? b_psi[e] : b_phi[e];
        const float4* Wr = (const float4*)(W + e * C_);
        const float4* Xr = (const float4*)(xbT + v * XS);
        #pragma unroll 8
        for (int cq = 0; cq < C_ / 4; ++cq) {
            float4 w4 = Wr[cq];
            float4 x4 = Xr[cq];
            s += w4.x * x4.x + w4.y * x4.y + w4.z * x4.z + w4.w * x4.w;
        }
        (m ? psi : phi)[j] = s;
    }
    __syncthreads();

    // ---- 3. attention scores: raw S[h][v][w] into Afin ----
    for (int i = tid; i < H_ * V_ * V_; i += 256) {
        int h = i / (V_ * V_);
        int r = i - h * V_ * V_;
        int v = r / V_;
        int w = r - v * V_;
        const float* ph = phi + (h * D_) * V_ + v;
        const float* ps = psi + (h * D_) * V_ + w;
        float s = 0.f;
        #pragma unroll
        for (int d = 0; d < D_; ++d)
            s += ph[d * V_] * ps[d * V_];
        Afin[i] = s * 0.17677669529663687f;  // 32^-0.5
    }
    __syncthreads();

    // ---- 4. softmax over w + combine with priors (75 rows) ----
    {
        float lam = lam_p[0];
        lam = fminf(fmaxf(lam, 0.f), 1.f);
        float beta = beta_p[0];
        if (tid < H_ * V_) {
            float* row = Afin + tid * V_;
            float mx = -1e30f;
            #pragma unroll
            for (int w = 0; w < V_; ++w) mx = fmaxf(mx, row[w]);
            float sum = 0.f;
            #pragma unroll
            for (int w = 0; w < V_; ++w) {
                float e = __expf(row[w] - mx);
                row[w] = e;
                sum += e;
            }
            float sc = lam / sum;
            const float* Ap = A_prior + tid * V_;
            const float* A2 = A_2hop + tid * V_;
            #pragma unroll
            for (int w = 0; w < V_; ++w)
                row[w] = Ap[w] + beta * A2[w] + sc * row[w];
        }
    }
    __syncthreads();

    // ---- 5. fused per-head M rows + gate logits, all in registers ----
    // thread tid owns output row o = tid:
    //   macc[h][w] = sum_c W_d[h,o,c] * xb[c,w]   (h = 0..2)
    //   macc[3][w] = sum_c W_g[o,c]   * xb[c,w]   (gate logits, bias later)
    float macc[4][V_];
    #pragma unroll
    for (int h = 0; h < 4; ++h)
        #pragma unroll
        for (int w = 0; w < V_; ++w) macc[h][w] = 0.f;

    const float4* Wd0 = (const float4*)(W_d + (size_t)(0 * O_ + tid) * C_);
    const float4* Wd1 = (const float4*)(W_d + (size_t)(1 * O_ + tid) * C_);
    const float4* Wd2 = (const float4*)(W_d + (size_t)(2 * O_ + tid) * C_);
    const float4* Wg  = (const float4*)(W_g + (size_t)tid * C_);
    for (int cq = 0; cq < C_ / 4; ++cq) {
        float4 w0 = Wd0[cq];
        float4 w1 = Wd1[cq];
        float4 w2 = Wd2[cq];
        float4 wg = Wg[cq];
        #pragma unroll
        for (int w = 0; w < V_; ++w) {
            float4 xq = *(const float4*)(xbT + w * XS + 4 * cq);  // wave-uniform broadcast
            macc[0][w] += w0.x * xq.x + w0.y * xq.y + w0.z * xq.z + w0.w * xq.w;
            macc[1][w] += w1.x * xq.x + w1.y * xq.y + w1.z * xq.z + w1.w * xq.w;
            macc[2][w] += w2.x * xq.x + w2.y * xq.y + w2.z * xq.z + w2.w * xq.w;
            macc[3][w] += wg.x * xq.x + wg.y * xq.y + wg.z * xq.z + wg.w * xq.w;
        }
    }

    // ---- 6. PV: acc[v] = sum_h sum_w Afin[h,v,w] * macc[h][w]  (+ sum_h b_d) ----
    float acc[V_];
    float bdsum = b_d[0 * O_ + tid] + b_d[1 * O_ + tid] + b_d[2 * O_ + tid];
    #pragma unroll
    for (int v = 0; v < V_; ++v) acc[v] = bdsum;
    #pragma unroll
    for (int h = 0; h < H_; ++h) {
        #pragma unroll
        for (int v = 0; v < V_; ++v) {
            const float* Ar = Afin + (h * V_ + v) * V_;
            float s = 0.f;
            #pragma unroll
            for (int w = 0; w < V_; ++w)
                s += Ar[w] * macc[h][w];
            acc[v] += s;
        }
    }

    // ---- 7. epilogue: BN + sigmoid gate + residual + relu, store ----
    float mean = bn_mean[tid];
    float var  = bn_var[tid];
    float gam  = bn_gamma[tid];
    float bnb  = bn_beta[tid];
    float bg   = b_g[tid];
    float inv  = rsqrtf(var + BN_EPS) * gam;
    float* op = out + xbase + (size_t)tid * (T_ * V_);  // out[n,tid,t,:] (O==C)
    #pragma unroll
    for (int v = 0; v < V_; ++v) {
        float pre = (acc[v] - mean) * inv + bnb;
        float gl  = macc[3][v] + bg;
        float g   = 1.f / (1.f + __expf(-gl));
        float r   = g * pre + xbT[v * XS + tid];
        op[v] = fmaxf(r, 0.f);
    }
}

extern "C" void kernel_launch(void* const* d_in, const int* in_sizes, int n_in,
                              void* d_out, int out_size, void* d_ws, size_t ws_size,
                              hipStream_t stream) {
    const float* x        = (const float*)d_in[0];
    const float* A_prior  = (const float*)d_in[1];
    const float* A_2hop   = (const float*)d_in[2];
    const float* beta_p   = (const float*)d_in[3];
    const float* lam_p    = (const float*)d_in[4];
    const float* W_phi    = (const float*)d_in[5];
    const float* b_phi    = (const float*)d_in[6];
    const float* W_psi    = (const float*)d_in[7];
    const float* b_psi    = (const float*)d_in[8];
    const float* W_d      = (const float*)d_in[9];
    const float* b_d      = (const float*)d_in[10];
    const float* bn_gamma = (const float*)d_in[11];
    const float* bn_beta  = (const float*)d_in[12];
    const float* bn_mean  = (const float*)d_in[13];
    const float* bn_var   = (const float*)d_in[14];
    const float* W_g      = (const float*)d_in[15];
    const float* b_g      = (const float*)d_in[16];
    float* out = (float*)d_out;

    dim3 grid(N_ * T_);
    dim3 block(256);
    hipLaunchKernelGGL(hdgc_fused, grid, block, 0, stream,
                       x, A_prior, A_2hop, beta_p, lam_p,
                       W_phi, b_phi, W_psi, b_psi,
                       W_d, b_d, bn_gamma, bn_beta, bn_mean, bn_var,
                       W_g, b_g, out);
}

// Round 6
// 464.563 us; speedup vs baseline: 5.8552x; 5.8552x over previous
//
#include <hip/hip_runtime.h>
#include <math.h>

#define N_ 64
#define C_ 256
#define T_ 64
#define V_ 25
#define H_ 3
#define O_ 256
#define D_ 32
#define HD_ 96

using short8 = __attribute__((ext_vector_type(8))) short;
using f32x4  = __attribute__((ext_vector_type(4))) float;

// d_ws layout in ushort (bf16) units, weights pre-swizzled to MFMA A-fragment order:
// tile = (row-tile ot, K-step ks); within tile: lane*8 + j, where
//   row = ot*16 + (lane&15), c = ks*32 + (lane>>4)*8 + j
#define WS_WD   0          // 3 heads * 16 ot * 8 ks * 512 = 196608
#define WS_WG   196608     // 16*8*512 = 65536
#define WS_WPHI 262144     // 6*8*512  = 24576
#define WS_WPSI 286720     // 6*8*512  = 24576   (total 311296 ushort = 622592 B)

__device__ __forceinline__ unsigned short f2bf(float f) {
    unsigned int u = __float_as_uint(f);
    unsigned int r = (u + 0x7fffu + ((u >> 16) & 1u)) >> 16;
    return (unsigned short)r;
}

__global__ __launch_bounds__(256)
void prep_weights(const float* __restrict__ Wd, const float* __restrict__ Wg,
                  const float* __restrict__ Wphi, const float* __restrict__ Wpsi,
                  unsigned short* __restrict__ ws) {
    int gid = blockIdx.x * 256 + threadIdx.x;
    if (gid >= 608 * 64) return;
    int tile = gid >> 6, lane = gid & 63;
    int lcol = lane & 15, lrow = lane >> 4;
    const float* W;
    unsigned short* base;
    int ot, ks;
    if (tile < 384) {                       // W_d: [h][o][c]
        int h = tile >> 7, r = tile & 127;
        ot = r >> 3; ks = r & 7;
        W = Wd + (size_t)h * O_ * C_;
        base = ws + WS_WD + (size_t)tile * 512;
    } else if (tile < 512) {                // W_g: [o][c]
        int r = tile - 384;
        ot = r >> 3; ks = r & 7;
        W = Wg;
        base = ws + WS_WG + (size_t)r * 512;
    } else if (tile < 560) {                // W_phi: [e][c]
        int r = tile - 512;
        ot = r >> 3; ks = r & 7;
        W = Wphi;
        base = ws + WS_WPHI + (size_t)r * 512;
    } else {                                // W_psi
        int r = tile - 560;
        ot = r >> 3; ks = r & 7;
        W = Wpsi;
        base = ws + WS_WPSI + (size_t)r * 512;
    }
    int row = ot * 16 + lcol;
    int c0  = ks * 32 + lrow * 8;
    const float* s = W + (size_t)row * C_ + c0;
    unsigned int p[4];
    #pragma unroll
    for (int q = 0; q < 4; ++q) {
        unsigned short lo = f2bf(s[2 * q]);
        unsigned short hi = f2bf(s[2 * q + 1]);
        p[q] = (unsigned int)lo | ((unsigned int)hi << 16);
    }
    uint4 pk = make_uint4(p[0], p[1], p[2], p[3]);
    *(uint4*)(base + (size_t)lane * 8) = pk;
}

// LDS map (bytes):
//   xbT  [32][256] bf16, XOR ^((v&7)<<4)        @ 0      (16384)
//   phiT [25][100] f32 ([v][e], pad 96->100)     @ 16384  (10000)
//   psiT [25][100] f32                           @ 26384  (10000)
//   Afin [3][32][32] bf16, XOR ^((v&7)<<4)       @ 36384  (6144)
//   Mlds [256][40] bf16 (per-head, reused)       @ 42528  (20480)   | S [3][25][28] f32 aliased
#define L_PHIT 16384
#define L_PSIT 26384
#define L_AFIN 36384
#define L_M    42528
#define L_TOT  63008

__global__ __launch_bounds__(256)
void hdgc_mfma(const float* __restrict__ x,
               const float* __restrict__ A_prior,
               const float* __restrict__ A_2hop,
               const float* __restrict__ beta_p,
               const float* __restrict__ lam_p,
               const float* __restrict__ b_phi,
               const float* __restrict__ b_psi,
               const unsigned short* __restrict__ ws,
               const float* __restrict__ b_d,
               const float* __restrict__ bn_gamma,
               const float* __restrict__ bn_beta,
               const float* __restrict__ bn_mean,
               const float* __restrict__ bn_var,
               const float* __restrict__ b_g,
               float* __restrict__ out) {
    __shared__ __align__(16) char lds[L_TOT];
    char*  xbT  = lds;
    float* phiT = (float*)(lds + L_PHIT);
    float* psiT = (float*)(lds + L_PSIT);
    char*  Afin = lds + L_AFIN;
    char*  Mlds = lds + L_M;
    float* Slds = (float*)(lds + L_M);

    const int tid  = threadIdx.x;
    const int lane = tid & 63, wid = tid >> 6;
    const int lcol = lane & 15, lrow = lane >> 4;
    const int b = blockIdx.x, n = b / T_, t = b - n * T_;
    const size_t xbase = (size_t)n * (C_ * T_ * V_) + (size_t)t * V_;

    // ---- stage: zero xbT pad rows + Afin, load x slice as bf16 (swizzled [v][c]) ----
    for (int i = tid; i < 7 * 256; i += 256) {          // rows v=25..31 -> 0
        int v = 25 + (i >> 8), c = i & 255;
        *(unsigned short*)(xbT + (((v << 9) + (c << 1)) ^ ((v & 7) << 4))) = 0;
    }
    for (int i = tid; i < 3 * 32 * 32; i += 256)
        ((unsigned short*)Afin)[i] = 0;
    for (int i = tid; i < C_ * V_; i += 256) {
        int c = i / V_, v = i - c * V_;
        unsigned short bv = f2bf(x[xbase + (size_t)c * (T_ * V_) + v]);
        *(unsigned short*)(xbT + (((v << 9) + (c << 1)) ^ ((v & 7) << 4))) = bv;
    }
    __syncthreads();

    // ---- phi/psi: MFMA, D written to [v][e] f32 (+bias) ----
    {
        const unsigned short* wsrc = ws + ((wid >> 1) ? WS_WPSI : WS_WPHI);
        const float* bias = (wid >> 1) ? b_psi : b_phi;
        float* dstT = (wid >> 1) ? psiT : phiT;
        int otbase = (wid & 1) * 3;
        f32x4 acc[3][2];
        #pragma unroll
        for (int oi = 0; oi < 3; ++oi)
            #pragma unroll
            for (int wt = 0; wt < 2; ++wt) acc[oi][wt] = (f32x4){0.f, 0.f, 0.f, 0.f};
        for (int ks = 0; ks < 8; ++ks) {
            const int cb = (ks * 32 + lrow * 8) << 1;
            short8 b0 = *(const short8*)(xbT + (((lcol << 9) + cb) ^ ((lcol & 7) << 4)));
            const int v1 = 16 + lcol;
            short8 b1 = *(const short8*)(xbT + (((v1 << 9) + cb) ^ ((v1 & 7) << 4)));
            #pragma unroll
            for (int oi = 0; oi < 3; ++oi) {
                int ot = otbase + oi;
                short8 a = *(const short8*)(wsrc + (((ot << 3) + ks) << 9) + lane * 8);
                acc[oi][0] = __builtin_amdgcn_mfma_f32_16x16x32_bf16(a, b0, acc[oi][0], 0, 0, 0);
                acc[oi][1] = __builtin_amdgcn_mfma_f32_16x16x32_bf16(a, b1, acc[oi][1], 0, 0, 0);
            }
        }
        #pragma unroll
        for (int oi = 0; oi < 3; ++oi) {
            int ot = otbase + oi;
            #pragma unroll
            for (int r = 0; r < 4; ++r) {
                int e = ot * 16 + lrow * 4 + r;
                float bv = bias[e];
                if (lcol < 25)      dstT[lcol * 100 + e]       = acc[oi][0][r] + bv;
                if (16 + lcol < 25) dstT[(16 + lcol) * 100 + e] = acc[oi][1][r] + bv;
            }
        }
    }
    __syncthreads();

    // ---- scores (VALU): S[h][v][w] = scale * sum_d phiT[v][h*32+d]*psiT[w][h*32+d] ----
    for (int it = tid; it < H_ * V_ * V_; it += 256) {
        int h = it / (V_ * V_), rem = it - h * V_ * V_;
        int v = rem / V_, w = rem - v * V_;
        const f32x4* pv = (const f32x4*)(phiT + v * 100 + h * 32);
        const f32x4* pw = (const f32x4*)(psiT + w * 100 + h * 32);
        float s = 0.f;
        #pragma unroll
        for (int q = 0; q < 8; ++q) {
            f32x4 a = pv[q], c = pw[q];
            s += a[0] * c[0] + a[1] * c[1] + a[2] * c[2] + a[3] * c[3];
        }
        Slds[(h * 25 + v) * 28 + w] = s * 0.17677669529663687f;
    }
    __syncthreads();

    // ---- softmax + combine priors -> Afin bf16 (swizzled [h*32+v][w]) ----
    if (tid < H_ * V_) {
        int h = tid / 25, v = tid - h * 25;
        float lam  = fminf(fmaxf(lam_p[0], 0.f), 1.f);
        float beta = beta_p[0];
        const float* row = Slds + tid * 28;
        float mx = -1e30f;
        #pragma unroll
        for (int w = 0; w < 25; ++w) mx = fmaxf(mx, row[w]);
        float e[25], sum = 0.f;
        #pragma unroll
        for (int w = 0; w < 25; ++w) { e[w] = __expf(row[w] - mx); sum += e[w]; }
        float sc = lam / sum;
        const float* Ap = A_prior + tid * 25;
        const float* A2 = A_2hop + tid * 25;
        #pragma unroll
        for (int w = 0; w < 25; ++w) {
            float af = Ap[w] + beta * A2[w] + sc * e[w];
            *(unsigned short*)(Afin + (((((h * 32 + v) << 6) + (w << 1))) ^ ((v & 7) << 4))) = f2bf(af);
        }
    }
    __syncthreads();

    // ---- per-head: M = W_d[h] @ xb (MFMA) -> Mlds bf16 ; PV: out += M @ Afin[h]^T ----
    f32x4 oacc[4][2], gacc[4][2];
    #pragma unroll
    for (int oi = 0; oi < 4; ++oi)
        #pragma unroll
        for (int vt = 0; vt < 2; ++vt) {
            oacc[oi][vt] = (f32x4){0.f, 0.f, 0.f, 0.f};
            gacc[oi][vt] = (f32x4){0.f, 0.f, 0.f, 0.f};
        }

    for (int h = 0; h < H_; ++h) {
        f32x4 macc[4][2];
        #pragma unroll
        for (int oi = 0; oi < 4; ++oi)
            #pragma unroll
            for (int wt = 0; wt < 2; ++wt) macc[oi][wt] = (f32x4){0.f, 0.f, 0.f, 0.f};
        for (int ks = 0; ks < 8; ++ks) {
            const int cb = (ks * 32 + lrow * 8) << 1;
            short8 b0 = *(const short8*)(xbT + (((lcol << 9) + cb) ^ ((lcol & 7) << 4)));
            const int v1 = 16 + lcol;
            short8 b1 = *(const short8*)(xbT + (((v1 << 9) + cb) ^ ((v1 & 7) << 4)));
            #pragma unroll
            for (int oi = 0; oi < 4; ++oi) {
                int ot = wid * 4 + oi;
                short8 a = *(const short8*)(ws + WS_WD + ((((h * 16 + ot) << 3) + ks) << 9) + lane * 8);
                macc[oi][0] = __builtin_amdgcn_mfma_f32_16x16x32_bf16(a, b0, macc[oi][0], 0, 0, 0);
                macc[oi][1] = __builtin_amdgcn_mfma_f32_16x16x32_bf16(a, b1, macc[oi][1], 0, 0, 0);
            }
        }
        #pragma unroll
        for (int oi = 0; oi < 4; ++oi) {
            int ot = wid * 4 + oi;
            #pragma unroll
            for (int r = 0; r < 4; ++r) {
                int o = ot * 16 + lrow * 4 + r;
                *(unsigned short*)(Mlds + o * 80 + (lcol << 1))        = f2bf(macc[oi][0][r]);
                *(unsigned short*)(Mlds + o * 80 + ((16 + lcol) << 1)) = f2bf(macc[oi][1][r]);
            }
        }
        __syncthreads();
        // PV: A-frag from Mlds (row o=lane&15, k=w), B-frag from Afin (col v=lane&15, k=w)
        {
            short8 af[4];
            #pragma unroll
            for (int oi = 0; oi < 4; ++oi) {
                int ot = wid * 4 + oi;
                af[oi] = *(const short8*)(Mlds + (ot * 16 + lcol) * 80 + (lrow << 4));
            }
            #pragma unroll
            for (int vt = 0; vt < 2; ++vt) {
                int v = vt * 16 + lcol;
                short8 bf = *(const short8*)(Afin + ((((h * 32 + v) << 6) + (lrow << 4)) ^ ((v & 7) << 4)));
                #pragma unroll
                for (int oi = 0; oi < 4; ++oi)
                    oacc[oi][vt] = __builtin_amdgcn_mfma_f32_16x16x32_bf16(af[oi], bf, oacc[oi][vt], 0, 0, 0);
            }
        }
        __syncthreads();
    }

    // ---- gate GEMM (kept in regs; D-layout matches oacc) ----
    for (int ks = 0; ks < 8; ++ks) {
        const int cb = (ks * 32 + lrow * 8) << 1;
        short8 b0 = *(const short8*)(xbT + (((lcol << 9) + cb) ^ ((lcol & 7) << 4)));
        const int v1 = 16 + lcol;
        short8 b1 = *(const short8*)(xbT + (((v1 << 9) + cb) ^ ((v1 & 7) << 4)));
        #pragma unroll
        for (int oi = 0; oi < 4; ++oi) {
            int ot = wid * 4 + oi;
            short8 a = *(const short8*)(ws + WS_WG + (((ot << 3) + ks) << 9) + lane * 8);
            gacc[oi][0] = __builtin_amdgcn_mfma_f32_16x16x32_bf16(a, b0, gacc[oi][0], 0, 0, 0);
            gacc[oi][1] = __builtin_amdgcn_mfma_f32_16x16x32_bf16(a, b1, gacc[oi][1], 0, 0, 0);
        }
    }

    // ---- epilogue: +b_d, BN, sigmoid gate, residual (bf16 x), relu, store ----
    #pragma unroll
    for (int oi = 0; oi < 4; ++oi) {
        int ot = wid * 4 + oi;
        #pragma unroll
        for (int r = 0; r < 4; ++r) {
            int o = ot * 16 + lrow * 4 + r;
            float bdsum = b_d[o] + b_d[O_ + o] + b_d[2 * O_ + o];
            float inv  = rsqrtf(bn_var[o] + 1e-5f) * bn_gamma[o];
            float mean = bn_mean[o], bnb = bn_beta[o], bg = b_g[o];
            float* op = out + xbase + (size_t)o * (T_ * V_);
            #pragma unroll
            for (int vt = 0; vt < 2; ++vt) {
                int v = vt * 16 + lcol;
                if (v < V_) {
                    float pre = (oacc[oi][vt][r] + bdsum - mean) * inv + bnb;
                    float gl  = gacc[oi][vt][r] + bg;
                    float g   = 1.f / (1.f + __expf(-gl));
                    unsigned short xb =
                        *(unsigned short*)(xbT + (((v << 9) + (o << 1)) ^ ((v & 7) << 4)));
                    float res = __uint_as_float(((unsigned int)xb) << 16);
                    float rr = g * pre + res;
                    op[v] = fmaxf(rr, 0.f);
                }
            }
        }
    }
}

extern "C" void kernel_launch(void* const* d_in, const int* in_sizes, int n_in,
                              void* d_out, int out_size, void* d_ws, size_t ws_size,
                              hipStream_t stream) {
    const float* x        = (const float*)d_in[0];
    const float* A_prior  = (const float*)d_in[1];
    const float* A_2hop   = (const float*)d_in[2];
    const float* beta_p   = (const float*)d_in[3];
    const float* lam_p    = (const float*)d_in[4];
    const float* W_phi    = (const float*)d_in[5];
    const float* b_phi    = (const float*)d_in[6];
    const float* W_psi    = (const float*)d_in[7];
    const float* b_psi    = (const float*)d_in[8];
    const float* W_d      = (const float*)d_in[9];
    const float* b_d      = (const float*)d_in[10];
    const float* bn_gamma = (const float*)d_in[11];
    const float* bn_beta  = (const float*)d_in[12];
    const float* bn_mean  = (const float*)d_in[13];
    const float* bn_var   = (const float*)d_in[14];
    const float* W_g      = (const float*)d_in[15];
    const float* b_g      = (const float*)d_in[16];
    unsigned short* ws = (unsigned short*)d_ws;
    float* out = (float*)d_out;

    hipLaunchKernelGGL(prep_weights, dim3(152), dim3(256), 0, stream,
                       W_d, W_g, W_phi, W_psi, ws);
    hipLaunchKernelGGL(hdgc_mfma, dim3(N_ * T_), dim3(256), 0, stream,
                       x, A_prior, A_2hop, beta_p, lam_p,
                       b_phi, b_psi, ws,
                       b_d, bn_gamma, bn_beta, bn_mean, bn_var, b_g, out);
}